// Round 1
// baseline (1398.431 us; speedup 1.0000x reference)
//
#include <hip/hip_runtime.h>
#include <hip/hip_bf16.h>

#define N_NODES 5000
#define N_EDGES 160000
#define HID 64
#define BATCH 2
#define TSTEPS 12
#define ROWS (BATCH*N_NODES)   // 10000

// ---------- precompute kernels (once per call) ----------

__global__ void k_count(const int* __restrict__ ei, int* __restrict__ cnt) {
  int e = blockIdx.x*blockDim.x + threadIdx.x;
  if (e < N_EDGES) atomicAdd(&cnt[ei[N_EDGES + e]], 1);
}

__global__ void k_scan(const int* __restrict__ cnt, int* __restrict__ row_ptr,
                       float* __restrict__ dinv) {
  __shared__ int sums[1024];
  int tid = threadIdx.x;
  constexpr int C = (N_NODES + 1023)/1024; // 5
  int base = tid*C;
  int local[C];
  int s = 0;
  #pragma unroll
  for (int i=0;i<C;i++){ int idx=base+i; int v=(idx<N_NODES)?cnt[idx]:0; local[i]=s; s+=v; }
  sums[tid]=s; __syncthreads();
  for (int off=1; off<1024; off<<=1) {
    int v = sums[tid];
    int add = (tid>=off)? sums[tid-off]:0;
    __syncthreads();
    sums[tid] = v + add;
    __syncthreads();
  }
  int excl = (tid>0)? sums[tid-1]:0;
  #pragma unroll
  for (int i=0;i<C;i++){ int idx=base+i; if(idx<N_NODES) row_ptr[idx]=excl+local[i]; }
  if (tid==0) row_ptr[N_NODES] = sums[1023];
  #pragma unroll
  for (int i=0;i<C;i++){ int idx=base+i; if(idx<N_NODES) dinv[idx]=rsqrtf((float)(cnt[idx]+1)); }
}

__global__ void k_fill(const int* __restrict__ ei, const int* __restrict__ row_ptr,
                       int* __restrict__ fill, int* __restrict__ csr_src) {
  int e = blockIdx.x*blockDim.x + threadIdx.x;
  if (e < N_EDGES) {
    int src = ei[e], dst = ei[N_EDGES+e];
    int pos = row_ptr[dst] + atomicAdd(&fill[dst],1);
    csr_src[pos] = src;
  }
}

// WT[k][j]: k<64 -> W_ih[j][k], k>=64 -> W_hh[j][k-64]   (gates j in [0,256))
__global__ void k_wt(const float* __restrict__ W_ih, const float* __restrict__ W_hh,
                     float* __restrict__ WT) {
  int idx = blockIdx.x*blockDim.x + threadIdx.x;
  if (idx < 128*256) {
    int k = idx >> 8, j = idx & 255;
    WT[idx] = (k < 64) ? W_ih[j*64 + k] : W_hh[j*64 + (k-64)];
  }
}

// bias[j] = b_ih[j] + b_hh[j] + sum_k b2[k]*W_ih[j][k]   (folds g2 = agg2 + b2)
__global__ void k_bias(const float* __restrict__ b_ih, const float* __restrict__ b_hh,
                       const float* __restrict__ b2, const float* __restrict__ W_ih,
                       float* __restrict__ bias) {
  int j = threadIdx.x;
  float s = b_ih[j] + b_hh[j];
  for (int k=0;k<64;k++) s = fmaf(b2[k], W_ih[j*64+k], s);
  bias[j] = s;
}

// ---------- per-timestep kernel AB: scalar SpMV p + hw2 = relu(p*W1+b1)@W2 ----------
__global__ void __launch_bounds__(256) k_ab(
    const float* __restrict__ x, int t,
    const float* __restrict__ W1, const float* __restrict__ b1,
    const float* __restrict__ W2,
    const int* __restrict__ row_ptr, const int* __restrict__ csr_src,
    const float* __restrict__ dinv, float* __restrict__ hw2)
{
  __shared__ float sW2[64*64];
  __shared__ float sW1[64], sb1[64];
  int tid = threadIdx.x;
  for (int i = tid; i < 4096; i += 256) sW2[i] = W2[i];
  if (tid < 64) { sW1[tid] = W1[tid]; sb1[tid] = b1[tid]; }
  __syncthreads();
  int r = blockIdx.x*4 + (tid>>6);     // grid is exactly ROWS/4 blocks
  int lane = tid & 63;
  int b = (r >= N_NODES) ? 1 : 0;
  int n = r - b*N_NODES;
  const float* xb = x + (size_t)(b*TSTEPS + t)*N_NODES;
  int e0 = row_ptr[n], e1 = row_ptr[n+1];
  float acc = 0.f;
  for (int e = e0 + lane; e < e1; e += 64) {
    int s = csr_src[e];
    acc += dinv[s]*xb[s];
  }
  #pragma unroll
  for (int m=32; m>=1; m>>=1) acc += __shfl_xor(acc, m, 64);
  float dn = dinv[n];
  float p = dn * (acc + dn*xb[n]);
  float a2 = 0.f;
  #pragma unroll
  for (int k=0;k<64;k++){
    float rv = fmaxf(fmaf(p, sW1[k], sb1[k]), 0.f);
    a2 = fmaf(rv, sW2[k*64+lane], a2);
  }
  hw2[(size_t)r*64 + lane] = a2;
}

// ---------- per-timestep kernel CD: SpMM aggregate (to LDS) + gate GEMM + LSTM update ----------
#define CD_ROWS 32
__global__ void __launch_bounds__(256) k_cd(
    const float* __restrict__ hw2,
    const int* __restrict__ row_ptr, const int* __restrict__ csr_src,
    const float* __restrict__ dinv,
    const float* __restrict__ WT, const float* __restrict__ bias,
    float* __restrict__ h, float* __restrict__ c)
{
  __shared__ float sA[CD_ROWS*132];   // [32][128+4]: cols 0..63 = agg2, 64..127 = h
  __shared__ float sB[32*260];        // WT chunk [32][256+4]; reused as gates [32][256]
  int tid = threadIdx.x;
  int r0 = blockIdx.x * CD_ROWS;
  int wv = tid >> 6, lane = tid & 63;

  // phase 1: per-row aggregation of hw2 over incoming edges (+self loop), and load h
  for (int lr = wv*8; lr < wv*8+8; ++lr) {
    int r = r0 + lr;
    float agg = 0.f, hval = 0.f;
    if (r < ROWS) {
      int b = (r >= N_NODES) ? 1 : 0;
      int n = r - b*N_NODES;
      const float* hwb = hw2 + (size_t)b*N_NODES*64;
      float dn = dinv[n];
      agg = dn*dn*hwb[(size_t)n*64 + lane];
      int e0 = row_ptr[n], e1 = row_ptr[n+1];
      for (int e=e0; e<e1; ++e) {
        int s = csr_src[e];
        agg = fmaf(dn*dinv[s], hwb[(size_t)s*64+lane], agg);
      }
      hval = h[(size_t)r*64 + lane];
    }
    sA[lr*132 + lane] = agg;
    sA[lr*132 + 64 + lane] = hval;
  }
  __syncthreads();

  // phase 2: gates[32][256] = [agg2|h] @ WT + bias, register-tiled 4x8
  int tr = tid >> 5;      // 0..7 -> rows 4*tr+ri
  int tc = tid & 31;      // cols 8*tc+ci
  float acc[4][8];
  {
    float4 bb0 = *(const float4*)&bias[8*tc];
    float4 bb1 = *(const float4*)&bias[8*tc+4];
    #pragma unroll
    for (int ri=0;ri<4;ri++){
      acc[ri][0]=bb0.x; acc[ri][1]=bb0.y; acc[ri][2]=bb0.z; acc[ri][3]=bb0.w;
      acc[ri][4]=bb1.x; acc[ri][5]=bb1.y; acc[ri][6]=bb1.z; acc[ri][7]=bb1.w;
    }
  }
  for (int ch=0; ch<4; ++ch) {
    for (int i = tid; i < 32*64; i += 256) {   // 2048 float4s
      int kk = i >> 6;
      int jj = (i & 63) * 4;
      *(float4*)&sB[kk*260 + jj] = *(const float4*)&WT[(ch*32+kk)*256 + jj];
    }
    __syncthreads();
    #pragma unroll 8
    for (int k=0;k<32;k++){
      int kg = ch*32 + k;
      float a0 = sA[(4*tr+0)*132 + kg];
      float a1 = sA[(4*tr+1)*132 + kg];
      float a2 = sA[(4*tr+2)*132 + kg];
      float a3 = sA[(4*tr+3)*132 + kg];
      float4 b0 = *(const float4*)&sB[k*260 + 8*tc];
      float4 b1 = *(const float4*)&sB[k*260 + 8*tc + 4];
      float bv[8] = {b0.x,b0.y,b0.z,b0.w,b1.x,b1.y,b1.z,b1.w};
      #pragma unroll
      for (int ci=0;ci<8;ci++){
        acc[0][ci] = fmaf(a0, bv[ci], acc[0][ci]);
        acc[1][ci] = fmaf(a1, bv[ci], acc[1][ci]);
        acc[2][ci] = fmaf(a2, bv[ci], acc[2][ci]);
        acc[3][ci] = fmaf(a3, bv[ci], acc[3][ci]);
      }
    }
    __syncthreads();
  }
  // stash gates in LDS (reuse sB)
  #pragma unroll
  for (int ri=0;ri<4;ri++){
    #pragma unroll
    for (int ci=0;ci<8;ci++){
      sB[(4*tr+ri)*256 + 8*tc+ci] = acc[ri][ci];
    }
  }
  __syncthreads();

  // phase 3: LSTM state update; thread -> row tid>>3, 8 consecutive h
  int lr = tid >> 3;
  int h0 = (tid & 7) * 8;
  int r = r0 + lr;
  if (r < ROWS) {
    #pragma unroll
    for (int hh=0; hh<8; ++hh) {
      int j = h0 + hh;
      float gi = sB[lr*256 + j];
      float gf = sB[lr*256 + 64 + j];
      float gg = sB[lr*256 + 128 + j];
      float go = sB[lr*256 + 192 + j];
      float si = 1.f/(1.f + __expf(-gi));
      float sf = 1.f/(1.f + __expf(-gf));
      float so = 1.f/(1.f + __expf(-go));
      float tg = tanhf(gg);
      float cold = c[(size_t)r*64 + j];
      float cn = sf*cold + si*tg;
      float hn = so*tanhf(cn);
      c[(size_t)r*64+j] = cn;
      h[(size_t)r*64+j] = hn;
    }
  }
}

// ---------- final projection ----------
__global__ void k_final(const float* __restrict__ h, const float* __restrict__ fc_w,
                        const float* __restrict__ fc_b, float* __restrict__ out) {
  int tid = threadIdx.x;
  int r = blockIdx.x*4 + (tid>>6);
  int lane = tid & 63;
  float v = h[(size_t)r*64+lane]*fc_w[lane];
  #pragma unroll
  for (int m=32;m>=1;m>>=1) v += __shfl_xor(v, m, 64);
  if (lane==0) out[r] = v + fc_b[0];
}

extern "C" void kernel_launch(void* const* d_in, const int* in_sizes, int n_in,
                              void* d_out, int out_size, void* d_ws, size_t ws_size,
                              hipStream_t stream) {
  const float* x    = (const float*)d_in[0];
  const int*   ei   = (const int*)d_in[1];
  const float* W1   = (const float*)d_in[2];
  const float* b1   = (const float*)d_in[3];
  const float* W2   = (const float*)d_in[4];
  const float* b2   = (const float*)d_in[5];
  const float* W_ih = (const float*)d_in[6];
  const float* W_hh = (const float*)d_in[7];
  const float* b_ih = (const float*)d_in[8];
  const float* b_hh = (const float*)d_in[9];
  const float* fc_w = (const float*)d_in[10];
  const float* fc_b = (const float*)d_in[11];
  float* out = (float*)d_out;

  char* ws = (char*)d_ws;
  size_t off = 0;
  auto alloc = [&](size_t bytes)->void* { void* p = ws + off; off += (bytes + 255) & ~255ul; return p; };
  float* dinv   = (float*)alloc(N_NODES*4);
  int*   cnt    = (int*)alloc(N_NODES*4);
  int*   row_ptr= (int*)alloc((N_NODES+1)*4);
  int*   fillb  = (int*)alloc(N_NODES*4);
  int*   csr_src= (int*)alloc(N_EDGES*4);
  float* WT     = (float*)alloc(128*256*4);
  float* bias   = (float*)alloc(256*4);
  float* hw2    = (float*)alloc((size_t)ROWS*64*4);
  float* h      = (float*)alloc((size_t)ROWS*64*4);
  float* c      = (float*)alloc((size_t)ROWS*64*4);

  hipMemsetAsync(cnt, 0, N_NODES*4, stream);
  hipMemsetAsync(fillb, 0, N_NODES*4, stream);
  hipMemsetAsync(h, 0, (size_t)ROWS*64*4, stream);
  hipMemsetAsync(c, 0, (size_t)ROWS*64*4, stream);

  k_count<<<(N_EDGES+255)/256, 256, 0, stream>>>(ei, cnt);
  k_scan<<<1, 1024, 0, stream>>>(cnt, row_ptr, dinv);
  k_fill<<<(N_EDGES+255)/256, 256, 0, stream>>>(ei, row_ptr, fillb, csr_src);
  k_wt<<<128, 256, 0, stream>>>(W_ih, W_hh, WT);
  k_bias<<<1, 256, 0, stream>>>(b_ih, b_hh, b2, W_ih, bias);

  for (int t=0; t<TSTEPS; ++t) {
    k_ab<<<ROWS/4, 256, 0, stream>>>(x, t, W1, b1, W2, row_ptr, csr_src, dinv, hw2);
    k_cd<<<(ROWS+CD_ROWS-1)/CD_ROWS, 256, 0, stream>>>(hw2, row_ptr, csr_src, dinv, WT, bias, h, c);
  }
  k_final<<<ROWS/4, 256, 0, stream>>>(h, fc_w, fc_b, out);
}

// Round 2
// 518.480 us; speedup vs baseline: 2.6972x; 2.6972x over previous
//
#include <hip/hip_runtime.h>

#define N_NODES 5000
#define N_EDGES 160000
#define BATCH 2
#define TSTEPS 12
#define ROWS (BATCH*N_NODES)   // 10000
#define GX_ROWS 16             // rows per block in gx/agg/lstm kernels (625 blocks)

// ---------------- precompute: CSR build, scales, weight transposes ----------------

__global__ void k_count(const int* __restrict__ ei, int* __restrict__ cnt) {
  int e = blockIdx.x*blockDim.x + threadIdx.x;
  if (e < N_EDGES) atomicAdd(&cnt[ei[N_EDGES + e]], 1);
}

__global__ void k_scan(const int* __restrict__ cnt, int* __restrict__ row_ptr,
                       float* __restrict__ dinv) {
  __shared__ int sums[1024];
  int tid = threadIdx.x;
  constexpr int C = (N_NODES + 1023)/1024; // 5
  int base = tid*C;
  int local[C];
  int s = 0;
  #pragma unroll
  for (int i=0;i<C;i++){ int idx=base+i; int v=(idx<N_NODES)?cnt[idx]:0; local[i]=s; s+=v; }
  sums[tid]=s; __syncthreads();
  for (int off=1; off<1024; off<<=1) {
    int v = sums[tid];
    int add = (tid>=off)? sums[tid-off]:0;
    __syncthreads();
    sums[tid] = v + add;
    __syncthreads();
  }
  int excl = (tid>0)? sums[tid-1]:0;
  #pragma unroll
  for (int i=0;i<C;i++){ int idx=base+i; if(idx<N_NODES) row_ptr[idx]=excl+local[i]; }
  if (tid==0) row_ptr[N_NODES] = sums[1023];
  #pragma unroll
  for (int i=0;i<C;i++){ int idx=base+i; if(idx<N_NODES) dinv[idx]=rsqrtf((float)(cnt[idx]+1)); }
}

__global__ void k_fill(const int* __restrict__ ei, const int* __restrict__ row_ptr,
                       int* __restrict__ fill, int* __restrict__ csr_src) {
  int e = blockIdx.x*blockDim.x + threadIdx.x;
  if (e < N_EDGES) {
    int src = ei[e], dst = ei[N_EDGES+e];
    int pos = row_ptr[dst] + atomicAdd(&fill[dst],1);
    csr_src[pos] = src;
  }
}

// xd[b,t,n] = x[b,t,n] * dinv[n]   (pre-scaled source values for layer-1 SpMV)
__global__ void k_xd(const float* __restrict__ x, const float* __restrict__ dinv,
                     float* __restrict__ xd) {
  int i = blockIdx.x*blockDim.x + threadIdx.x;
  if (i < BATCH*TSTEPS*N_NODES) xd[i] = x[i] * dinv[i % N_NODES];
}

// WT[k][j]: rows 0..63 = W_ih^T, rows 64..127 = W_hh^T  (j in [0,256))
__global__ void k_wt2(const float* __restrict__ W_ih, const float* __restrict__ W_hh,
                      float* __restrict__ WT) {
  int idx = blockIdx.x*blockDim.x + threadIdx.x;
  if (idx < 64*256) {
    int k = idx >> 8, j = idx & 255;
    WT[idx]           = W_ih[j*64 + k];
    WT[64*256 + idx]  = W_hh[j*64 + k];
  }
}

// biasT[j] = b_ih[j] + b_hh[j] + sum_k b2[k]*W_ih[j][k]
__global__ void k_bias(const float* __restrict__ b_ih, const float* __restrict__ b_hh,
                       const float* __restrict__ b2, const float* __restrict__ W_ih,
                       float* __restrict__ biasT) {
  int j = threadIdx.x;
  float s = b_ih[j] + b_hh[j];
  for (int k=0;k<64;k++) s = fmaf(b2[k], W_ih[j*64+k], s);
  biasT[j] = s;
}

// ---------------- stage 1 (all t): hw2d = dinv[n] * (relu(p*W1+b1) @ W2) ----------------
__global__ void __launch_bounds__(256) k_hw(
    const float* __restrict__ xd,
    const float* __restrict__ W1, const float* __restrict__ b1,
    const float* __restrict__ W2,
    const int* __restrict__ row_ptr, const int* __restrict__ csr_src,
    const float* __restrict__ dinv, float* __restrict__ hw2d)
{
  __shared__ float sW2[4096];
  __shared__ float sW1[64], sb1[64];
  int tid = threadIdx.x;
  for (int i = tid; i < 4096; i += 256) sW2[i] = W2[i];
  if (tid < 64) { sW1[tid] = W1[tid]; sb1[tid] = b1[tid]; }
  __syncthreads();
  int t  = blockIdx.x / (ROWS/GX_ROWS);
  int rb = blockIdx.x % (ROWS/GX_ROWS);
  int wv = tid >> 6, lane = tid & 63;
  for (int lr = wv*4; lr < wv*4+4; ++lr) {
    int r = rb*GX_ROWS + lr;
    int b = (r >= N_NODES) ? 1 : 0;
    int n = r - b*N_NODES;
    const float* xb = xd + (size_t)(b*TSTEPS + t)*N_NODES;
    int e0 = row_ptr[n], e1 = row_ptr[n+1];
    float acc = 0.f;
    for (int e = e0 + lane; e < e1; e += 64) acc += xb[csr_src[e]];
    #pragma unroll
    for (int m=32; m>=1; m>>=1) acc += __shfl_xor(acc, m, 64);
    float dn = dinv[n];
    float p = dn * (acc + xb[n]);      // xb pre-scaled by dinv[src]
    float a2 = 0.f;
    #pragma unroll
    for (int k=0;k<64;k++){
      float rv = fmaxf(fmaf(p, sW1[k], sb1[k]), 0.f);
      a2 = fmaf(rv, sW2[k*64+lane], a2);
    }
    hw2d[((size_t)(t*BATCH+b)*N_NODES + n)*64 + lane] = dn * a2;
  }
}

// ---------------- stage 2A (all t): gates_x = agg2 @ W_ih^T + biasT ----------------
__global__ void __launch_bounds__(256) k_gx_full(
    const float* __restrict__ hw2d,
    const int* __restrict__ row_ptr, const int* __restrict__ csr_src,
    const float* __restrict__ dinv,
    const float* __restrict__ WT,      // first 64 rows = W_ih^T
    const float* __restrict__ biasT,
    float* __restrict__ gates_x)
{
  __shared__ float sA[GX_ROWS*68];
  __shared__ float sB[32*260];
  int tid = threadIdx.x;
  int t  = blockIdx.x / (ROWS/GX_ROWS);
  int rb = blockIdx.x % (ROWS/GX_ROWS);
  int r0 = rb*GX_ROWS;
  int wv = tid >> 6, lane = tid & 63;
  // phase 1: aggregation (pre-scaled gathers, 4-deep ILP)
  for (int lr = wv*4; lr < wv*4+4; ++lr) {
    int r = r0 + lr;
    int b = (r >= N_NODES) ? 1 : 0;
    int n = r - b*N_NODES;
    const float* hwb = hw2d + (size_t)(t*BATCH+b)*N_NODES*64;
    int e0 = row_ptr[n], e1 = row_ptr[n+1];
    float a0=0.f,a1=0.f,a2=0.f,a3=0.f;
    int e = e0;
    for (; e+3 < e1; e += 4) {
      int s0=csr_src[e], s1=csr_src[e+1], s2=csr_src[e+2], s3=csr_src[e+3];
      a0 += hwb[(size_t)s0*64+lane];
      a1 += hwb[(size_t)s1*64+lane];
      a2 += hwb[(size_t)s2*64+lane];
      a3 += hwb[(size_t)s3*64+lane];
    }
    for (; e < e1; ++e) a0 += hwb[(size_t)csr_src[e]*64+lane];
    float dn = dinv[n];
    sA[lr*68+lane] = dn * (((a0+a1)+(a2+a3)) + hwb[(size_t)n*64+lane]);
  }
  __syncthreads();
  // phase 2: [16x64] @ [64x256] + biasT
  int tr = tid >> 5, tc = tid & 31;   // rows 2tr+ri, cols 8tc..
  float acc[2][8];
  {
    float4 bb0 = *(const float4*)&biasT[8*tc];
    float4 bb1 = *(const float4*)&biasT[8*tc+4];
    #pragma unroll
    for (int ri=0;ri<2;ri++){
      acc[ri][0]=bb0.x; acc[ri][1]=bb0.y; acc[ri][2]=bb0.z; acc[ri][3]=bb0.w;
      acc[ri][4]=bb1.x; acc[ri][5]=bb1.y; acc[ri][6]=bb1.z; acc[ri][7]=bb1.w;
    }
  }
  for (int ch=0; ch<2; ++ch) {
    for (int i = tid; i < 32*64; i += 256) {
      int kk = i >> 6, jj = (i & 63)*4;
      *(float4*)&sB[kk*260 + jj] = *(const float4*)&WT[(ch*32+kk)*256 + jj];
    }
    __syncthreads();
    #pragma unroll
    for (int k=0;k<32;k++){
      int kg = ch*32 + k;
      float a0 = sA[(2*tr+0)*68 + kg];
      float a1 = sA[(2*tr+1)*68 + kg];
      float4 b0 = *(const float4*)&sB[k*260 + 8*tc];
      float4 b1 = *(const float4*)&sB[k*260 + 8*tc + 4];
      float bv[8] = {b0.x,b0.y,b0.z,b0.w,b1.x,b1.y,b1.z,b1.w};
      #pragma unroll
      for (int ci=0;ci<8;ci++){
        acc[0][ci] = fmaf(a0, bv[ci], acc[0][ci]);
        acc[1][ci] = fmaf(a1, bv[ci], acc[1][ci]);
      }
    }
    __syncthreads();
  }
  #pragma unroll
  for (int ri=0;ri<2;ri++){
    float* gp = &gates_x[((size_t)t*ROWS + r0 + 2*tr + ri)*256 + 8*tc];
    float4 o0 = {acc[ri][0],acc[ri][1],acc[ri][2],acc[ri][3]};
    float4 o1 = {acc[ri][4],acc[ri][5],acc[ri][6],acc[ri][7]};
    *(float4*)gp = o0;
    *(float4*)(gp+4) = o1;
  }
}

// ---------------- stage 2B (small-ws fallback): agg2 only ----------------
__global__ void __launch_bounds__(256) k_agg(
    const float* __restrict__ hw2d,
    const int* __restrict__ row_ptr, const int* __restrict__ csr_src,
    const float* __restrict__ dinv, float* __restrict__ agg2)
{
  int tid = threadIdx.x;
  int t  = blockIdx.x / (ROWS/GX_ROWS);
  int rb = blockIdx.x % (ROWS/GX_ROWS);
  int wv = tid >> 6, lane = tid & 63;
  for (int lr = wv*4; lr < wv*4+4; ++lr) {
    int r = rb*GX_ROWS + lr;
    int b = (r >= N_NODES) ? 1 : 0;
    int n = r - b*N_NODES;
    const float* hwb = hw2d + (size_t)(t*BATCH+b)*N_NODES*64;
    int e0 = row_ptr[n], e1 = row_ptr[n+1];
    float a0=0.f,a1=0.f,a2=0.f,a3=0.f;
    int e = e0;
    for (; e+3 < e1; e += 4) {
      int s0=csr_src[e], s1=csr_src[e+1], s2=csr_src[e+2], s3=csr_src[e+3];
      a0 += hwb[(size_t)s0*64+lane];
      a1 += hwb[(size_t)s1*64+lane];
      a2 += hwb[(size_t)s2*64+lane];
      a3 += hwb[(size_t)s3*64+lane];
    }
    for (; e < e1; ++e) a0 += hwb[(size_t)csr_src[e]*64+lane];
    float dn = dinv[n];
    agg2[((size_t)t*ROWS + r)*64 + lane] =
        dn * (((a0+a1)+(a2+a3)) + hwb[(size_t)n*64+lane]);
  }
}

// ---------------- stage 3A: persistent 12-step LSTM, K=64 ----------------
__global__ void __launch_bounds__(128) k_lstm64(
    const float* __restrict__ gates_x, const float* __restrict__ WThh,
    const float* __restrict__ fc_w, const float* __restrict__ fc_b,
    float* __restrict__ out)
{
  __shared__ float sH[GX_ROWS*68];
  __shared__ float sB[32*260];     // W chunk; reused as gates[16][260]
  int tid = threadIdx.x;
  int r0 = blockIdx.x*GX_ROWS;
  int tr = tid >> 5, tc = tid & 31;     // GEMM: rows 4tr+ri
  int lr = tid >> 3, hc0 = (tid & 7)*8; // update: row lr, cols hc0..hc0+7
  float creg[8], hn[8];
  #pragma unroll
  for (int j=0;j<8;j++){ creg[j]=0.f; hn[j]=0.f; }
  for (int t=0; t<TSTEPS; ++t) {
    float acc[4][8];
    #pragma unroll
    for (int ri=0;ri<4;ri++){
      const float* gp = &gates_x[((size_t)t*ROWS + r0 + 4*tr + ri)*256 + 8*tc];
      float4 g0 = *(const float4*)gp;
      float4 g1 = *(const float4*)(gp+4);
      acc[ri][0]=g0.x; acc[ri][1]=g0.y; acc[ri][2]=g0.z; acc[ri][3]=g0.w;
      acc[ri][4]=g1.x; acc[ri][5]=g1.y; acc[ri][6]=g1.z; acc[ri][7]=g1.w;
    }
    if (t > 0) {
      for (int ch=0; ch<2; ++ch) {
        for (int i = tid; i < 2048; i += 128) {
          int kk = i >> 6, jj = (i & 63)*4;
          *(float4*)&sB[kk*260 + jj] = *(const float4*)&WThh[(ch*32+kk)*256 + jj];
        }
        __syncthreads();
        #pragma unroll
        for (int k=0;k<32;k++){
          int kg = ch*32 + k;
          float a0 = sH[(4*tr+0)*68 + kg];
          float a1 = sH[(4*tr+1)*68 + kg];
          float a2 = sH[(4*tr+2)*68 + kg];
          float a3 = sH[(4*tr+3)*68 + kg];
          float4 b0 = *(const float4*)&sB[k*260 + 8*tc];
          float4 b1 = *(const float4*)&sB[k*260 + 8*tc + 4];
          float bv[8] = {b0.x,b0.y,b0.z,b0.w,b1.x,b1.y,b1.z,b1.w};
          #pragma unroll
          for (int ci=0;ci<8;ci++){
            acc[0][ci] = fmaf(a0, bv[ci], acc[0][ci]);
            acc[1][ci] = fmaf(a1, bv[ci], acc[1][ci]);
            acc[2][ci] = fmaf(a2, bv[ci], acc[2][ci]);
            acc[3][ci] = fmaf(a3, bv[ci], acc[3][ci]);
          }
        }
        __syncthreads();
      }
    }
    // stash gates
    #pragma unroll
    for (int ri=0;ri<4;ri++){
      float4 o0={acc[ri][0],acc[ri][1],acc[ri][2],acc[ri][3]};
      float4 o1={acc[ri][4],acc[ri][5],acc[ri][6],acc[ri][7]};
      *(float4*)&sB[(4*tr+ri)*260 + 8*tc]     = o0;
      *(float4*)&sB[(4*tr+ri)*260 + 8*tc + 4] = o1;
    }
    __syncthreads();
    // LSTM update
    #pragma unroll
    for (int j=0;j<8;j++){
      int col = hc0 + j;
      float gi = sB[lr*260 + col];
      float gf = sB[lr*260 + 64 + col];
      float gg = sB[lr*260 + 128 + col];
      float go = sB[lr*260 + 192 + col];
      float si = 1.f/(1.f + __expf(-gi));
      float sf = 1.f/(1.f + __expf(-gf));
      float so = 1.f/(1.f + __expf(-go));
      float tg = tanhf(gg);
      float cn = sf*creg[j] + si*tg;
      creg[j] = cn;
      hn[j] = so*tanhf(cn);
      sH[lr*68 + col] = hn[j];
    }
    __syncthreads();
  }
  float v = 0.f;
  #pragma unroll
  for (int j=0;j<8;j++) v = fmaf(hn[j], fc_w[hc0+j], v);
  v += __shfl_xor(v, 1, 64);
  v += __shfl_xor(v, 2, 64);
  v += __shfl_xor(v, 4, 64);
  if ((tid & 7) == 0) out[r0 + lr] = v + fc_b[0];
}

// ---------------- stage 3B: persistent 12-step LSTM, K=128 (fallback) ----------------
__global__ void __launch_bounds__(128) k_lstm128(
    const float* __restrict__ agg2, const float* __restrict__ WT, // [128][256]
    const float* __restrict__ biasT,
    const float* __restrict__ fc_w, const float* __restrict__ fc_b,
    float* __restrict__ out)
{
  __shared__ float sA[GX_ROWS*132];  // cols 0..63 agg, 64..127 h
  __shared__ float sB[32*260];
  int tid = threadIdx.x;
  int r0 = blockIdx.x*GX_ROWS;
  int tr = tid >> 5, tc = tid & 31;
  int lr = tid >> 3, hc0 = (tid & 7)*8;
  float creg[8], hn[8];
  #pragma unroll
  for (int j=0;j<8;j++){ creg[j]=0.f; hn[j]=0.f; }
  for (int i=tid; i<GX_ROWS*132; i+=128) sA[i] = 0.f;
  __syncthreads();
  for (int t=0; t<TSTEPS; ++t) {
    for (int i = tid; i < GX_ROWS*16; i += 128) {     // 16 rows x 16 float4
      int rr = i >> 4, jj = (i & 15)*4;
      *(float4*)&sA[rr*132 + jj] = *(const float4*)&agg2[((size_t)t*ROWS + r0 + rr)*64 + jj];
    }
    __syncthreads();
    float acc[4][8];
    {
      float4 bb0 = *(const float4*)&biasT[8*tc];
      float4 bb1 = *(const float4*)&biasT[8*tc+4];
      #pragma unroll
      for (int ri=0;ri<4;ri++){
        acc[ri][0]=bb0.x; acc[ri][1]=bb0.y; acc[ri][2]=bb0.z; acc[ri][3]=bb0.w;
        acc[ri][4]=bb1.x; acc[ri][5]=bb1.y; acc[ri][6]=bb1.z; acc[ri][7]=bb1.w;
      }
    }
    int nch = (t > 0) ? 4 : 2;    // h==0 at t=0: skip W_hh chunks
    for (int ch=0; ch<nch; ++ch) {
      for (int i = tid; i < 2048; i += 128) {
        int kk = i >> 6, jj = (i & 63)*4;
        *(float4*)&sB[kk*260 + jj] = *(const float4*)&WT[(ch*32+kk)*256 + jj];
      }
      __syncthreads();
      #pragma unroll
      for (int k=0;k<32;k++){
        int kg = ch*32 + k;
        float a0 = sA[(4*tr+0)*132 + kg];
        float a1 = sA[(4*tr+1)*132 + kg];
        float a2 = sA[(4*tr+2)*132 + kg];
        float a3 = sA[(4*tr+3)*132 + kg];
        float4 b0 = *(const float4*)&sB[k*260 + 8*tc];
        float4 b1 = *(const float4*)&sB[k*260 + 8*tc + 4];
        float bv[8] = {b0.x,b0.y,b0.z,b0.w,b1.x,b1.y,b1.z,b1.w};
        #pragma unroll
        for (int ci=0;ci<8;ci++){
          acc[0][ci] = fmaf(a0, bv[ci], acc[0][ci]);
          acc[1][ci] = fmaf(a1, bv[ci], acc[1][ci]);
          acc[2][ci] = fmaf(a2, bv[ci], acc[2][ci]);
          acc[3][ci] = fmaf(a3, bv[ci], acc[3][ci]);
        }
      }
      __syncthreads();
    }
    #pragma unroll
    for (int ri=0;ri<4;ri++){
      float4 o0={acc[ri][0],acc[ri][1],acc[ri][2],acc[ri][3]};
      float4 o1={acc[ri][4],acc[ri][5],acc[ri][6],acc[ri][7]};
      *(float4*)&sB[(4*tr+ri)*260 + 8*tc]     = o0;
      *(float4*)&sB[(4*tr+ri)*260 + 8*tc + 4] = o1;
    }
    __syncthreads();
    #pragma unroll
    for (int j=0;j<8;j++){
      int col = hc0 + j;
      float gi = sB[lr*260 + col];
      float gf = sB[lr*260 + 64 + col];
      float gg = sB[lr*260 + 128 + col];
      float go = sB[lr*260 + 192 + col];
      float si = 1.f/(1.f + __expf(-gi));
      float sf = 1.f/(1.f + __expf(-gf));
      float so = 1.f/(1.f + __expf(-go));
      float tg = tanhf(gg);
      float cn = sf*creg[j] + si*tg;
      creg[j] = cn;
      hn[j] = so*tanhf(cn);
      sA[lr*132 + 64 + col] = hn[j];
    }
    __syncthreads();
  }
  float v = 0.f;
  #pragma unroll
  for (int j=0;j<8;j++) v = fmaf(hn[j], fc_w[hc0+j], v);
  v += __shfl_xor(v, 1, 64);
  v += __shfl_xor(v, 2, 64);
  v += __shfl_xor(v, 4, 64);
  if ((tid & 7) == 0) out[r0 + lr] = v + fc_b[0];
}

extern "C" void kernel_launch(void* const* d_in, const int* in_sizes, int n_in,
                              void* d_out, int out_size, void* d_ws, size_t ws_size,
                              hipStream_t stream) {
  const float* x    = (const float*)d_in[0];
  const int*   ei   = (const int*)d_in[1];
  const float* W1   = (const float*)d_in[2];
  const float* b1   = (const float*)d_in[3];
  const float* W2   = (const float*)d_in[4];
  const float* b2   = (const float*)d_in[5];
  const float* W_ih = (const float*)d_in[6];
  const float* W_hh = (const float*)d_in[7];
  const float* b_ih = (const float*)d_in[8];
  const float* b_hh = (const float*)d_in[9];
  const float* fc_w = (const float*)d_in[10];
  const float* fc_b = (const float*)d_in[11];
  float* out = (float*)d_out;

  char* ws = (char*)d_ws;
  size_t off = 0;
  auto alloc = [&](size_t bytes)->void* { void* p = ws + off; off += (bytes + 255) & ~255ul; return p; };
  float* dinv    = (float*)alloc(N_NODES*4);
  int*   cnt     = (int*)alloc(N_NODES*4);
  int*   row_ptr = (int*)alloc((N_NODES+1)*4);
  int*   fillb   = (int*)alloc(N_NODES*4);
  int*   csr_src = (int*)alloc(N_EDGES*4);
  float* WT      = (float*)alloc(128*256*4);           // [0:64)=W_ih^T, [64:128)=W_hh^T
  float* biasT   = (float*)alloc(256*4);
  float* xd      = (float*)alloc((size_t)BATCH*TSTEPS*N_NODES*4);
  float* hw2d    = (float*)alloc((size_t)TSTEPS*BATCH*N_NODES*64*4);

  hipMemsetAsync(cnt,  0, N_NODES*4, stream);
  hipMemsetAsync(fillb,0, N_NODES*4, stream);

  k_count<<<(N_EDGES+255)/256, 256, 0, stream>>>(ei, cnt);
  k_scan <<<1, 1024, 0, stream>>>(cnt, row_ptr, dinv);
  k_fill <<<(N_EDGES+255)/256, 256, 0, stream>>>(ei, row_ptr, fillb, csr_src);
  k_xd   <<<(BATCH*TSTEPS*N_NODES+255)/256, 256, 0, stream>>>(x, dinv, xd);
  k_wt2  <<<(64*256+255)/256, 256, 0, stream>>>(W_ih, W_hh, WT);
  k_bias <<<1, 256, 0, stream>>>(b_ih, b_hh, b2, W_ih, biasT);

  k_hw<<<TSTEPS*(ROWS/GX_ROWS), 256, 0, stream>>>(xd, W1, b1, W2, row_ptr, csr_src, dinv, hw2d);

  size_t gates_bytes = (size_t)TSTEPS*ROWS*256*4;   // ~123 MB
  if (ws_size >= off + gates_bytes) {
    float* gates_x = (float*)alloc(gates_bytes);
    k_gx_full<<<TSTEPS*(ROWS/GX_ROWS), 256, 0, stream>>>(hw2d, row_ptr, csr_src, dinv, WT, biasT, gates_x);
    k_lstm64<<<ROWS/GX_ROWS, 128, 0, stream>>>(gates_x, WT + 64*256, fc_w, fc_b, out);
  } else {
    float* agg2 = (float*)alloc((size_t)TSTEPS*ROWS*64*4);  // ~31 MB
    k_agg<<<TSTEPS*(ROWS/GX_ROWS), 256, 0, stream>>>(hw2d, row_ptr, csr_src, dinv, agg2);
    k_lstm128<<<ROWS/GX_ROWS, 128, 0, stream>>>(agg2, WT, biasT, fc_w, fc_b, out);
  }
}

// Round 3
// 252.978 us; speedup vs baseline: 5.5279x; 2.0495x over previous
//
#include <hip/hip_runtime.h>

#define N_NODES 5000
#define N_EDGES 160000
#define BATCH 2
#define TSTEPS 12
#define ROWS (BATCH*N_NODES)   // 10000
#define RB 16                  // rows per block
#define NRB (ROWS/RB)          // 625

typedef short short8_t __attribute__((ext_vector_type(8)));
typedef float f32x4 __attribute__((ext_vector_type(4)));

__device__ inline unsigned short f2bf(float f){
  union { float f; unsigned u; } v; v.f = f;
  unsigned r = v.u + 0x7fff + ((v.u >> 16) & 1);   // RNE
  return (unsigned short)(r >> 16);
}
__device__ inline float bf2f(unsigned short s){
  union { unsigned u; float f; } v; v.u = ((unsigned)s) << 16;
  return v.f;
}

// ---------------- precompute ----------------

__global__ void k_count(const int* __restrict__ ei, int* __restrict__ cnt) {
  int e = blockIdx.x*blockDim.x + threadIdx.x;
  if (e < N_EDGES) atomicAdd(&cnt[ei[N_EDGES + e]], 1);
}

__global__ void k_scan(const int* __restrict__ cnt, int* __restrict__ row_ptr,
                       float* __restrict__ dinv) {
  __shared__ int sums[1024];
  int tid = threadIdx.x;
  constexpr int C = (N_NODES + 1023)/1024; // 5
  int base = tid*C;
  int local[C];
  int s = 0;
  #pragma unroll
  for (int i=0;i<C;i++){ int idx=base+i; int v=(idx<N_NODES)?cnt[idx]:0; local[i]=s; s+=v; }
  sums[tid]=s; __syncthreads();
  for (int off=1; off<1024; off<<=1) {
    int v = sums[tid];
    int add = (tid>=off)? sums[tid-off]:0;
    __syncthreads();
    sums[tid] = v + add;
    __syncthreads();
  }
  int excl = (tid>0)? sums[tid-1]:0;
  #pragma unroll
  for (int i=0;i<C;i++){ int idx=base+i; if(idx<N_NODES) row_ptr[idx]=excl+local[i]; }
  if (tid==0) row_ptr[N_NODES] = sums[1023];
  #pragma unroll
  for (int i=0;i<C;i++){ int idx=base+i; if(idx<N_NODES) dinv[idx]=rsqrtf((float)(cnt[idx]+1)); }
}

__global__ void k_fill(const int* __restrict__ ei, const int* __restrict__ row_ptr,
                       int* __restrict__ fill, int* __restrict__ csr_src) {
  int e = blockIdx.x*blockDim.x + threadIdx.x;
  if (e < N_EDGES) {
    int src = ei[e], dst = ei[N_EDGES+e];
    int pos = row_ptr[dst] + atomicAdd(&fill[dst],1);
    csr_src[pos] = src;
  }
}

__global__ void k_xd(const float* __restrict__ x, const float* __restrict__ dinv,
                     float* __restrict__ xd) {
  int i = blockIdx.x*blockDim.x + threadIdx.x;
  if (i < BATCH*TSTEPS*N_NODES) xd[i] = x[i] * dinv[i % N_NODES];
}

// Build split-bf16 B-fragments for MFMA 16x16x32, laid out in fragment order:
// WF[ ((which*2+kt)*16+ct)*1024 + hl*512 + lane*8 + j ]
//   value = W[col][k],  col = ct*16 + (lane&15),  k = kt*32 + (lane>>4)*8 + j
//   which 0 = W_ih, 1 = W_hh; hl 0 = hi, 1 = lo.
__global__ void k_wf(const float* __restrict__ W_ih, const float* __restrict__ W_hh,
                     unsigned short* __restrict__ WF) {
  int idx = blockIdx.x*256 + threadIdx.x;    // 0..4095
  int lane  = idx & 63;
  int ct    = (idx >> 6) & 15;
  int kt    = (idx >> 10) & 1;
  int which = idx >> 11;
  const float* W = which ? W_hh : W_ih;
  int col = ct*16 + (lane & 15);
  int k0  = kt*32 + (lane >> 4)*8;
  size_t base = ((size_t)((which*2+kt)*16 + ct))*1024 + (size_t)lane*8;
  #pragma unroll
  for (int j=0;j<8;j++){
    float w = W[col*64 + k0 + j];
    unsigned short hi = f2bf(w);
    unsigned short lo = f2bf(w - bf2f(hi));
    WF[base + j]       = hi;
    WF[base + 512 + j] = lo;
  }
}

// biasT[j] = b_ih[j] + b_hh[j] + sum_k b2[k]*W_ih[j][k]
__global__ void k_bias(const float* __restrict__ b_ih, const float* __restrict__ b_hh,
                       const float* __restrict__ b2, const float* __restrict__ W_ih,
                       float* __restrict__ biasT) {
  int j = threadIdx.x;
  float s = b_ih[j] + b_hh[j];
  for (int k=0;k<64;k++) s = fmaf(b2[k], W_ih[j*64+k], s);
  biasT[j] = s;
}

// ---------------- stage 1 (all t): hw2d = dinv[n] * (relu(p*W1+b1) @ W2) ----------------
__global__ void __launch_bounds__(256) k_hw(
    const float* __restrict__ xd,
    const float* __restrict__ W1, const float* __restrict__ b1,
    const float* __restrict__ W2,
    const int* __restrict__ row_ptr, const int* __restrict__ csr_src,
    const float* __restrict__ dinv, float* __restrict__ hw2d)
{
  __shared__ float sW2[4096];
  __shared__ float sW1[64], sb1[64];
  int tid = threadIdx.x;
  for (int i = tid; i < 4096; i += 256) sW2[i] = W2[i];
  if (tid < 64) { sW1[tid] = W1[tid]; sb1[tid] = b1[tid]; }
  __syncthreads();
  int t  = blockIdx.x / NRB;
  int rb = blockIdx.x % NRB;
  int wv = tid >> 6, lane = tid & 63;
  float p[4], dn[4];
  int nn[4], bb[4];
  #pragma unroll
  for (int i=0;i<4;i++){
    int r = rb*RB + wv*4 + i;
    int b = (r >= N_NODES) ? 1 : 0;
    int n = r - b*N_NODES;
    const float* xb = xd + (size_t)(b*TSTEPS + t)*N_NODES;
    int e0 = row_ptr[n], e1 = row_ptr[n+1];
    float acc = 0.f;
    for (int e = e0 + lane; e < e1; e += 64) acc += xb[csr_src[e]];
    #pragma unroll
    for (int m=32; m>=1; m>>=1) acc += __shfl_xor(acc, m, 64);
    dn[i] = dinv[n];
    p[i]  = dn[i] * (acc + xb[n]);   // xd pre-scaled by dinv[src]
    nn[i] = n; bb[i] = b;
  }
  float a[4] = {0.f,0.f,0.f,0.f};
  #pragma unroll 8
  for (int k=0;k<64;k++){
    float w2 = sW2[k*64 + lane];
    float w1 = sW1[k], bk = sb1[k];
    #pragma unroll
    for (int i=0;i<4;i++)
      a[i] = fmaf(fmaxf(fmaf(p[i], w1, bk), 0.f), w2, a[i]);
  }
  #pragma unroll
  for (int i=0;i<4;i++)
    hw2d[((size_t)(t*BATCH+bb[i])*N_NODES + nn[i])*64 + lane] = dn[i]*a[i];
}

// ---------------- stage 2 (all t): gates_x = agg2 @ W_ih^T + biasT  (MFMA split-bf16) ----------------
__global__ void __launch_bounds__(256) k_gx(
    const float* __restrict__ hw2d,
    const int* __restrict__ row_ptr, const int* __restrict__ csr_src,
    const float* __restrict__ dinv,
    const unsigned short* __restrict__ WF,    // which=0 fragments
    const float* __restrict__ biasT,
    float* __restrict__ gates_x)
{
  __shared__ float sA[RB*68];   // [16 rows][64 k] f32, stride 68
  int tid = threadIdx.x;
  int t  = blockIdx.x / NRB;
  int rb = blockIdx.x % NRB;
  int r0 = rb*RB;
  int wv = tid >> 6, lane = tid & 63;
  int eg = lane >> 4, g = lane & 15;

  // phase 1: aggregation — float4 gathers, 4 edges per instruction
  #pragma unroll
  for (int i=0;i<4;i++){
    int lr = wv*4 + i;
    int r = r0 + lr;
    int b = (r >= N_NODES) ? 1 : 0;
    int n = r - b*N_NODES;
    const float* hwb = hw2d + (size_t)(t*BATCH+b)*N_NODES*64;
    int e0 = row_ptr[n], e1 = row_ptr[n+1];
    float ax=0.f, ay=0.f, az=0.f, aw=0.f;
    float bx=0.f, by=0.f, bz=0.f, bw=0.f;
    int e = e0 + eg;
    for (; e + 4 < e1; e += 8){
      int sa = csr_src[e], sb = csr_src[e+4];
      float4 va = *(const float4*)(hwb + (size_t)sa*64 + 4*g);
      float4 vb = *(const float4*)(hwb + (size_t)sb*64 + 4*g);
      ax += va.x; ay += va.y; az += va.z; aw += va.w;
      bx += vb.x; by += vb.y; bz += vb.z; bw += vb.w;
    }
    if (e < e1){
      int sa = csr_src[e];
      float4 va = *(const float4*)(hwb + (size_t)sa*64 + 4*g);
      ax += va.x; ay += va.y; az += va.z; aw += va.w;
    }
    ax += bx; ay += by; az += bz; aw += bw;
    ax += __shfl_xor(ax, 16, 64); ax += __shfl_xor(ax, 32, 64);
    ay += __shfl_xor(ay, 16, 64); ay += __shfl_xor(ay, 32, 64);
    az += __shfl_xor(az, 16, 64); az += __shfl_xor(az, 32, 64);
    aw += __shfl_xor(aw, 16, 64); aw += __shfl_xor(aw, 32, 64);
    float4 sv = *(const float4*)(hwb + (size_t)n*64 + 4*g);
    float dn = dinv[n];
    if (eg == 0){
      float4 o;
      o.x = dn*(ax + sv.x); o.y = dn*(ay + sv.y);
      o.z = dn*(az + sv.z); o.w = dn*(aw + sv.w);
      *(float4*)&sA[lr*68 + 4*g] = o;
    }
  }
  __syncthreads();

  // phase 2: MFMA. A-frag: row = lane&15, k = kt*32 + (lane>>4)*8 + j (consistent with WF).
  int row = lane & 15, kg = lane >> 4;
  short8_t Ah[2], Al[2];
  #pragma unroll
  for (int kt=0; kt<2; kt++){
    const float* ap = &sA[row*68 + kt*32 + kg*8];
    float4 x0 = *(const float4*)ap;
    float4 x1 = *(const float4*)(ap + 4);
    float xs[8] = {x0.x,x0.y,x0.z,x0.w,x1.x,x1.y,x1.z,x1.w};
    #pragma unroll
    for (int j=0;j<8;j++){
      unsigned short h = f2bf(xs[j]);
      unsigned short l = f2bf(xs[j] - bf2f(h));
      Ah[kt][j] = (short)h;
      Al[kt][j] = (short)l;
    }
  }
  f32x4 acc[4];
  #pragma unroll
  for (int i=0;i<4;i++){
    int ct = wv*4 + i;
    f32x4 a = {0.f,0.f,0.f,0.f};
    #pragma unroll
    for (int kt=0; kt<2; kt++){
      size_t base = ((size_t)(kt*16 + ct))*1024 + (size_t)lane*8;
      short8_t bh = *(const short8_t*)(WF + base);
      short8_t bl = *(const short8_t*)(WF + base + 512);
      a = __builtin_amdgcn_mfma_f32_16x16x32_bf16(Ah[kt], bh, a, 0, 0, 0);
      a = __builtin_amdgcn_mfma_f32_16x16x32_bf16(Ah[kt], bl, a, 0, 0, 0);
      a = __builtin_amdgcn_mfma_f32_16x16x32_bf16(Al[kt], bh, a, 0, 0, 0);
    }
    acc[i] = a;
  }
  // epilogue: D layout col = lane&15, row = (lane>>4)*4 + reg
  #pragma unroll
  for (int i=0;i<4;i++){
    int ct = wv*4 + i;
    int col = ct*16 + row;
    float bs = biasT[col];
    #pragma unroll
    for (int rr=0;rr<4;rr++){
      int orow = kg*4 + rr;
      gates_x[((size_t)t*ROWS + r0 + orow)*256 + col] = acc[i][rr] + bs;
    }
  }
}

// ---------------- stage 3: persistent 12-step LSTM (MFMA split-bf16 for h@W_hh^T) ----------------
__global__ void __launch_bounds__(256) k_lstm(
    const float* __restrict__ gates_x,
    const unsigned short* __restrict__ WFhh,   // which=1 fragments (same indexing as WF)
    const float* __restrict__ fc_w, const float* __restrict__ fc_b,
    float* __restrict__ out)
{
  __shared__ unsigned short sHh[RB*72];   // h hi, bf16, row stride 72
  __shared__ unsigned short sHl[RB*72];   // h lo
  __shared__ float sG[RB*260];            // gates [16][256+4]
  int tid = threadIdx.x;
  int r0 = blockIdx.x*RB;
  int wv = tid >> 6, lane = tid & 63;
  int row = lane & 15, kg = lane >> 4;
  int urow = tid >> 4, uc0 = (tid & 15)*4;   // update mapping: 16 rows x 16 col-quads

  float creg[4] = {0.f,0.f,0.f,0.f};
  float hn[4]   = {0.f,0.f,0.f,0.f};
  float pre[4][4];
  // prefetch gates for t=0
  #pragma unroll
  for (int i=0;i<4;i++){
    int col = (wv*4+i)*16 + row;
    #pragma unroll
    for (int rr=0;rr<4;rr++)
      pre[i][rr] = gates_x[((size_t)(r0 + kg*4 + rr))*256 + col];
  }

  for (int t=0; t<TSTEPS; ++t){
    f32x4 acc[4];
    #pragma unroll
    for (int i=0;i<4;i++){
      acc[i][0]=pre[i][0]; acc[i][1]=pre[i][1]; acc[i][2]=pre[i][2]; acc[i][3]=pre[i][3];
    }
    if (t+1 < TSTEPS){
      #pragma unroll
      for (int i=0;i<4;i++){
        int col = (wv*4+i)*16 + row;
        #pragma unroll
        for (int rr=0;rr<4;rr++)
          pre[i][rr] = gates_x[((size_t)(t+1)*ROWS + r0 + kg*4 + rr)*256 + col];
      }
    }
    if (t > 0){
      short8_t Ah[2], Al[2];
      #pragma unroll
      for (int kt=0; kt<2; kt++){
        int hoff = row*72 + kt*32 + kg*8;
        Ah[kt] = *(const short8_t*)&sHh[hoff];
        Al[kt] = *(const short8_t*)&sHl[hoff];
      }
      #pragma unroll
      for (int i=0;i<4;i++){
        int ct = wv*4 + i;
        f32x4 a = acc[i];
        #pragma unroll
        for (int kt=0; kt<2; kt++){
          size_t base = ((size_t)(kt*16 + ct))*1024 + (size_t)lane*8;
          short8_t bh = *(const short8_t*)(WFhh + base);
          short8_t bl = *(const short8_t*)(WFhh + base + 512);
          a = __builtin_amdgcn_mfma_f32_16x16x32_bf16(Ah[kt], bh, a, 0, 0, 0);
          a = __builtin_amdgcn_mfma_f32_16x16x32_bf16(Ah[kt], bl, a, 0, 0, 0);
          a = __builtin_amdgcn_mfma_f32_16x16x32_bf16(Al[kt], bh, a, 0, 0, 0);
        }
        acc[i] = a;
      }
    }
    // stash gates to LDS
    #pragma unroll
    for (int i=0;i<4;i++){
      int col = (wv*4+i)*16 + row;
      #pragma unroll
      for (int rr=0;rr<4;rr++)
        sG[(kg*4+rr)*260 + col] = acc[i][rr];
    }
    __syncthreads();
    // LSTM update
    {
      float4 gi = *(const float4*)&sG[urow*260 + uc0];
      float4 gf = *(const float4*)&sG[urow*260 + 64  + uc0];
      float4 gg = *(const float4*)&sG[urow*260 + 128 + uc0];
      float4 go = *(const float4*)&sG[urow*260 + 192 + uc0];
      float gis[4] = {gi.x,gi.y,gi.z,gi.w};
      float gfs[4] = {gf.x,gf.y,gf.z,gf.w};
      float ggs[4] = {gg.x,gg.y,gg.z,gg.w};
      float gos[4] = {go.x,go.y,go.z,go.w};
      unsigned short hh[4], hl[4];
      #pragma unroll
      for (int j=0;j<4;j++){
        float si = 1.f/(1.f + __expf(-gis[j]));
        float sf = 1.f/(1.f + __expf(-gfs[j]));
        float so = 1.f/(1.f + __expf(-gos[j]));
        float tg = tanhf(ggs[j]);
        float cn = sf*creg[j] + si*tg;
        creg[j] = cn;
        hn[j] = so*tanhf(cn);
        hh[j] = f2bf(hn[j]);
        hl[j] = f2bf(hn[j] - bf2f(hh[j]));
      }
      unsigned w0 = (unsigned)hh[0] | ((unsigned)hh[1] << 16);
      unsigned w1 = (unsigned)hh[2] | ((unsigned)hh[3] << 16);
      unsigned v0 = (unsigned)hl[0] | ((unsigned)hl[1] << 16);
      unsigned v1 = (unsigned)hl[2] | ((unsigned)hl[3] << 16);
      *(uint2*)&sHh[urow*72 + uc0] = make_uint2(w0, w1);
      *(uint2*)&sHl[urow*72 + uc0] = make_uint2(v0, v1);
    }
    __syncthreads();
  }
  // final projection: out[r] = sum_j h[r][j]*fc_w[j] + fc_b
  float4 fw = *(const float4*)&fc_w[uc0];
  float v = hn[0]*fw.x + hn[1]*fw.y + hn[2]*fw.z + hn[3]*fw.w;
  v += __shfl_xor(v, 1, 64);
  v += __shfl_xor(v, 2, 64);
  v += __shfl_xor(v, 4, 64);
  v += __shfl_xor(v, 8, 64);
  if ((lane & 15) == 0) out[r0 + urow] = v + fc_b[0];
}

extern "C" void kernel_launch(void* const* d_in, const int* in_sizes, int n_in,
                              void* d_out, int out_size, void* d_ws, size_t ws_size,
                              hipStream_t stream) {
  const float* x    = (const float*)d_in[0];
  const int*   ei   = (const int*)d_in[1];
  const float* W1   = (const float*)d_in[2];
  const float* b1   = (const float*)d_in[3];
  const float* W2   = (const float*)d_in[4];
  const float* b2   = (const float*)d_in[5];
  const float* W_ih = (const float*)d_in[6];
  const float* W_hh = (const float*)d_in[7];
  const float* b_ih = (const float*)d_in[8];
  const float* b_hh = (const float*)d_in[9];
  const float* fc_w = (const float*)d_in[10];
  const float* fc_b = (const float*)d_in[11];
  float* out = (float*)d_out;

  char* ws = (char*)d_ws;
  size_t off = 0;
  auto alloc = [&](size_t bytes)->void* { void* p = ws + off; off += (bytes + 255) & ~255ul; return p; };
  float*          dinv    = (float*)alloc(N_NODES*4);
  int*            cnt     = (int*)alloc(N_NODES*4);
  int*            row_ptr = (int*)alloc((N_NODES+1)*4);
  int*            fillb   = (int*)alloc(N_NODES*4);
  int*            csr_src = (int*)alloc(N_EDGES*4);
  unsigned short* WF      = (unsigned short*)alloc(2*2*16*1024*2);  // 128 KB
  float*          biasT   = (float*)alloc(256*4);
  float*          xd      = (float*)alloc((size_t)BATCH*TSTEPS*N_NODES*4);
  float*          hw2d    = (float*)alloc((size_t)TSTEPS*BATCH*N_NODES*64*4);   // ~30.7 MB
  float*          gates_x = (float*)alloc((size_t)TSTEPS*ROWS*256*4);           // ~123 MB

  hipMemsetAsync(cnt,  0, N_NODES*4, stream);
  hipMemsetAsync(fillb,0, N_NODES*4, stream);

  k_count<<<(N_EDGES+255)/256, 256, 0, stream>>>(ei, cnt);
  k_scan <<<1, 1024, 0, stream>>>(cnt, row_ptr, dinv);
  k_fill <<<(N_EDGES+255)/256, 256, 0, stream>>>(ei, row_ptr, fillb, csr_src);
  k_xd   <<<(BATCH*TSTEPS*N_NODES+255)/256, 256, 0, stream>>>(x, dinv, xd);
  k_wf   <<<16, 256, 0, stream>>>(W_ih, W_hh, WF);
  k_bias <<<1, 256, 0, stream>>>(b_ih, b_hh, b2, W_ih, biasT);

  k_hw  <<<TSTEPS*NRB, 256, 0, stream>>>(xd, W1, b1, W2, row_ptr, csr_src, dinv, hw2d);
  k_gx  <<<TSTEPS*NRB, 256, 0, stream>>>(hw2d, row_ptr, csr_src, dinv, WF, biasT, gates_x);
  k_lstm<<<NRB, 256, 0, stream>>>(gates_x, WF + 2*16*1024, fc_w, fc_b, out);
}

// Round 4
// 202.727 us; speedup vs baseline: 6.8981x; 1.2479x over previous
//
#include <hip/hip_runtime.h>

#define N_NODES 5000
#define N_EDGES 160000
#define BATCH 2
#define TSTEPS 12
#define ROWS (BATCH*N_NODES)   // 10000
#define RB 16                  // rows per block
#define NRB (ROWS/RB)          // 625

typedef short short8_t __attribute__((ext_vector_type(8)));
typedef float f32x4 __attribute__((ext_vector_type(4)));

__device__ inline unsigned short f2bf(float f){
  union { float f; unsigned u; } v; v.f = f;
  unsigned r = v.u + 0x7fff + ((v.u >> 16) & 1);   // RNE
  return (unsigned short)(r >> 16);
}
__device__ inline float bf2f(unsigned short s){
  union { unsigned u; float f; } v; v.u = ((unsigned)s) << 16;
  return v.f;
}

// Bijective XCD swizzle for grid 7500 = 8*937+4: XCD x gets a contiguous work
// chunk, so each XCD's L2 sees ~1.5 timestep slices of hw2d (3.8MB <= 4MB L2).
__device__ inline int swz7500(int gid){
  int xcd = gid & 7, i = gid >> 3;
  return (xcd < 4 ? xcd*938 : 3752 + (xcd-4)*937) + i;
}

// ---------------- precompute ----------------

__global__ void k_count(const int* __restrict__ ei, int* __restrict__ cnt) {
  int e = blockIdx.x*blockDim.x + threadIdx.x;
  if (e < N_EDGES) atomicAdd(&cnt[ei[N_EDGES + e]], 1);
}

__global__ void k_scan(const int* __restrict__ cnt, int* __restrict__ row_ptr,
                       float* __restrict__ dinv) {
  __shared__ int sums[1024];
  int tid = threadIdx.x;
  constexpr int C = (N_NODES + 1023)/1024; // 5
  int base = tid*C;
  int local[C];
  int s = 0;
  #pragma unroll
  for (int i=0;i<C;i++){ int idx=base+i; int v=(idx<N_NODES)?cnt[idx]:0; local[i]=s; s+=v; }
  sums[tid]=s; __syncthreads();
  for (int off=1; off<1024; off<<=1) {
    int v = sums[tid];
    int add = (tid>=off)? sums[tid-off]:0;
    __syncthreads();
    sums[tid] = v + add;
    __syncthreads();
  }
  int excl = (tid>0)? sums[tid-1]:0;
  #pragma unroll
  for (int i=0;i<C;i++){ int idx=base+i; if(idx<N_NODES) row_ptr[idx]=excl+local[i]; }
  if (tid==0) row_ptr[N_NODES] = sums[1023];
  #pragma unroll
  for (int i=0;i<C;i++){ int idx=base+i; if(idx<N_NODES) dinv[idx]=rsqrtf((float)(cnt[idx]+1)); }
}

__global__ void k_fill(const int* __restrict__ ei, const int* __restrict__ row_ptr,
                       int* __restrict__ fill, int* __restrict__ csr_src) {
  int e = blockIdx.x*blockDim.x + threadIdx.x;
  if (e < N_EDGES) {
    int src = ei[e], dst = ei[N_EDGES+e];
    int pos = row_ptr[dst] + atomicAdd(&fill[dst],1);
    csr_src[pos] = src;
  }
}

__global__ void k_xd(const float* __restrict__ x, const float* __restrict__ dinv,
                     float* __restrict__ xd) {
  int i = blockIdx.x*blockDim.x + threadIdx.x;
  if (i < BATCH*TSTEPS*N_NODES) xd[i] = x[i] * dinv[i % N_NODES];
}

// Merged: blocks 0..15 build split-bf16 B-fragments (WF), block 16 builds biasT.
// WF[ (kt4*16+ct)*1024 + hl*512 + lane*8 + j ], kt4 = which*2+kt in 0..3
//   value = W[col][k], col = ct*16+(lane&15), k = kt*32+(lane>>4)*8+j
__global__ void k_wfb(const float* __restrict__ W_ih, const float* __restrict__ W_hh,
                      const float* __restrict__ b_ih, const float* __restrict__ b_hh,
                      const float* __restrict__ b2,
                      unsigned short* __restrict__ WF, float* __restrict__ biasT) {
  if (blockIdx.x == 16) {
    int j = threadIdx.x;
    float s = b_ih[j] + b_hh[j];
    for (int k=0;k<64;k++) s = fmaf(b2[k], W_ih[j*64+k], s);
    biasT[j] = s;
    return;
  }
  int idx = blockIdx.x*256 + threadIdx.x;    // 0..4095
  int lane  = idx & 63;
  int ct    = (idx >> 6) & 15;
  int kt    = (idx >> 10) & 1;
  int which = idx >> 11;
  const float* W = which ? W_hh : W_ih;
  int col = ct*16 + (lane & 15);
  int k0  = kt*32 + (lane >> 4)*8;
  size_t base = ((size_t)((which*2+kt)*16 + ct))*1024 + (size_t)lane*8;
  #pragma unroll
  for (int j=0;j<8;j++){
    float w = W[col*64 + k0 + j];
    unsigned short hi = f2bf(w);
    unsigned short lo = f2bf(w - bf2f(hi));
    WF[base + j]       = hi;
    WF[base + 512 + j] = lo;
  }
}

// ---------------- stage 1 (all t): hw2d = dinv[n] * (relu(p*W1+b1) @ W2) ----------------
__global__ void __launch_bounds__(256) k_hw(
    const float* __restrict__ xd,
    const float* __restrict__ W1, const float* __restrict__ b1,
    const float* __restrict__ W2,
    const int* __restrict__ row_ptr, const int* __restrict__ csr_src,
    const float* __restrict__ dinv, float* __restrict__ hw2d)
{
  __shared__ float sW2[4096];
  __shared__ float sW1[64], sb1[64];
  int tid = threadIdx.x;
  for (int i = tid; i < 4096; i += 256) sW2[i] = W2[i];
  if (tid < 64) { sW1[tid] = W1[tid]; sb1[tid] = b1[tid]; }
  __syncthreads();
  int wk = swz7500(blockIdx.x);
  int t  = wk / NRB;
  int rb = wk % NRB;
  int wv = tid >> 6, lane = tid & 63;
  float p[4], dn[4];
  int nn[4], bb[4];
  #pragma unroll
  for (int i=0;i<4;i++){
    int r = rb*RB + wv*4 + i;
    int b = (r >= N_NODES) ? 1 : 0;
    int n = r - b*N_NODES;
    const float* xb = xd + (size_t)(b*TSTEPS + t)*N_NODES;
    int e0 = row_ptr[n], e1 = row_ptr[n+1];
    float acc = 0.f;
    for (int e = e0 + lane; e < e1; e += 64) acc += xb[csr_src[e]];
    #pragma unroll
    for (int m=32; m>=1; m>>=1) acc += __shfl_xor(acc, m, 64);
    dn[i] = dinv[n];
    p[i]  = dn[i] * (acc + xb[n]);   // xd pre-scaled by dinv[src]
    nn[i] = n; bb[i] = b;
  }
  float a[4] = {0.f,0.f,0.f,0.f};
  #pragma unroll 8
  for (int k=0;k<64;k++){
    float w2 = sW2[k*64 + lane];
    float w1 = sW1[k], bk = sb1[k];
    #pragma unroll
    for (int i=0;i<4;i++)
      a[i] = fmaf(fmaxf(fmaf(p[i], w1, bk), 0.f), w2, a[i]);
  }
  #pragma unroll
  for (int i=0;i<4;i++)
    hw2d[((size_t)(t*BATCH+bb[i])*N_NODES + nn[i])*64 + lane] = dn[i]*a[i];
}

// ---------------- stage 2 (all t): agg2 = D^-1/2 (A+I) D^-1/2 hw2 (pure gather) ----------------
__global__ void __launch_bounds__(256) k_agg(
    const float* __restrict__ hw2d,
    const int* __restrict__ row_ptr, const int* __restrict__ csr_src,
    const float* __restrict__ dinv, float* __restrict__ agg2)
{
  int tid = threadIdx.x;
  int wk = swz7500(blockIdx.x);
  int t  = wk / NRB;
  int rb = wk % NRB;
  int r0 = rb*RB;
  int wv = tid >> 6, lane = tid & 63;
  int eg = lane >> 4, g = lane & 15;
  #pragma unroll
  for (int i=0;i<4;i++){
    int lr = wv*4 + i;
    int r = r0 + lr;
    int b = (r >= N_NODES) ? 1 : 0;
    int n = r - b*N_NODES;
    const float* hwb = hw2d + (size_t)(t*BATCH+b)*N_NODES*64;
    int e0 = row_ptr[n], e1 = row_ptr[n+1];
    float ax=0.f, ay=0.f, az=0.f, aw=0.f;
    float bx=0.f, by=0.f, bz=0.f, bw=0.f;
    int e = e0 + eg;
    for (; e + 4 < e1; e += 8){
      int sa = csr_src[e], sb = csr_src[e+4];
      float4 va = *(const float4*)(hwb + (size_t)sa*64 + 4*g);
      float4 vb = *(const float4*)(hwb + (size_t)sb*64 + 4*g);
      ax += va.x; ay += va.y; az += va.z; aw += va.w;
      bx += vb.x; by += vb.y; bz += vb.z; bw += vb.w;
    }
    if (e < e1){
      int sa = csr_src[e];
      float4 va = *(const float4*)(hwb + (size_t)sa*64 + 4*g);
      ax += va.x; ay += va.y; az += va.z; aw += va.w;
    }
    ax += bx; ay += by; az += bz; aw += bw;
    ax += __shfl_xor(ax, 16, 64); ax += __shfl_xor(ax, 32, 64);
    ay += __shfl_xor(ay, 16, 64); ay += __shfl_xor(ay, 32, 64);
    az += __shfl_xor(az, 16, 64); az += __shfl_xor(az, 32, 64);
    aw += __shfl_xor(aw, 16, 64); aw += __shfl_xor(aw, 32, 64);
    if (eg == 0){
      float4 sv = *(const float4*)(hwb + (size_t)n*64 + 4*g);
      float dn = dinv[n];
      float4 o;
      o.x = dn*(ax + sv.x); o.y = dn*(ay + sv.y);
      o.z = dn*(az + sv.z); o.w = dn*(aw + sv.w);
      *(float4*)&agg2[((size_t)t*ROWS + r)*64 + 4*g] = o;
    }
  }
}

// ---------------- stage 3: persistent 12-step LSTM, K=128 MFMA [agg | h] ----------------
__global__ void __launch_bounds__(256) k_lstm(
    const float* __restrict__ agg2,
    const unsigned short* __restrict__ WF,   // 4 kt-tiles: 0,1=W_ih  2,3=W_hh
    const float* __restrict__ biasT,
    const float* __restrict__ fc_w, const float* __restrict__ fc_b,
    float* __restrict__ out)
{
  __shared__ unsigned short sHh[RB*72];   // h hi, bf16, row stride 72
  __shared__ unsigned short sHl[RB*72];   // h lo
  __shared__ float sG[RB*260];            // gates [16][256+4]
  int tid = threadIdx.x;
  int r0 = blockIdx.x*RB;
  int wv = tid >> 6, lane = tid & 63;
  int row = lane & 15, kg = lane >> 4;
  int urow = tid >> 4, uc0 = (tid & 15)*4;   // update mapping: 16 rows x 16 col-quads

  float creg[4] = {0.f,0.f,0.f,0.f};
  float hn[4]   = {0.f,0.f,0.f,0.f};

  // prefetch agg A-tile for t=0: lane (row,kg) loads 8 f32 per kt (coalesced 4KB/wave)
  float4 p00,p01,p10,p11;
  {
    const float* base = &agg2[((size_t)(r0 + row))*64 + kg*8];
    p00 = *(const float4*)base;      p01 = *(const float4*)(base+4);
    p10 = *(const float4*)(base+32); p11 = *(const float4*)(base+36);
  }

  for (int t=0; t<TSTEPS; ++t){
    // convert current agg prefetch to split-bf16 A-fragments (kt 0,1)
    short8_t Ah[2], Al[2];
    {
      float xs0[8] = {p00.x,p00.y,p00.z,p00.w,p01.x,p01.y,p01.z,p01.w};
      float xs1[8] = {p10.x,p10.y,p10.z,p10.w,p11.x,p11.y,p11.z,p11.w};
      #pragma unroll
      for (int j=0;j<8;j++){
        unsigned short h0 = f2bf(xs0[j]);
        Ah[0][j] = (short)h0; Al[0][j] = (short)f2bf(xs0[j] - bf2f(h0));
        unsigned short h1 = f2bf(xs1[j]);
        Ah[1][j] = (short)h1; Al[1][j] = (short)f2bf(xs1[j] - bf2f(h1));
      }
    }
    // issue next-t prefetch
    if (t+1 < TSTEPS){
      const float* base = &agg2[((size_t)(t+1)*ROWS + r0 + row)*64 + kg*8];
      p00 = *(const float4*)base;      p01 = *(const float4*)(base+4);
      p10 = *(const float4*)(base+32); p11 = *(const float4*)(base+36);
    }
    // h A-fragments from LDS (kt 2,3), valid for t>0
    short8_t Hh[2], Hl[2];
    if (t > 0){
      #pragma unroll
      for (int kt=0; kt<2; kt++){
        int hoff = row*72 + kt*32 + kg*8;
        Hh[kt] = *(const short8_t*)&sHh[hoff];
        Hl[kt] = *(const short8_t*)&sHl[hoff];
      }
    }
    f32x4 acc[4];
    #pragma unroll
    for (int i=0;i<4;i++){
      float bs = biasT[(wv*4+i)*16 + row];
      acc[i][0]=bs; acc[i][1]=bs; acc[i][2]=bs; acc[i][3]=bs;
    }
    #pragma unroll
    for (int i=0;i<4;i++){
      int ct = wv*4 + i;
      f32x4 a = acc[i];
      #pragma unroll
      for (int kt=0; kt<2; kt++){
        size_t base = ((size_t)(kt*16 + ct))*1024 + (size_t)lane*8;
        short8_t bh = *(const short8_t*)(WF + base);
        short8_t bl = *(const short8_t*)(WF + base + 512);
        a = __builtin_amdgcn_mfma_f32_16x16x32_bf16(Ah[kt], bh, a, 0, 0, 0);
        a = __builtin_amdgcn_mfma_f32_16x16x32_bf16(Ah[kt], bl, a, 0, 0, 0);
        a = __builtin_amdgcn_mfma_f32_16x16x32_bf16(Al[kt], bh, a, 0, 0, 0);
      }
      if (t > 0){
        #pragma unroll
        for (int kt=0; kt<2; kt++){
          size_t base = ((size_t)((2+kt)*16 + ct))*1024 + (size_t)lane*8;
          short8_t bh = *(const short8_t*)(WF + base);
          short8_t bl = *(const short8_t*)(WF + base + 512);
          a = __builtin_amdgcn_mfma_f32_16x16x32_bf16(Hh[kt], bh, a, 0, 0, 0);
          a = __builtin_amdgcn_mfma_f32_16x16x32_bf16(Hh[kt], bl, a, 0, 0, 0);
          a = __builtin_amdgcn_mfma_f32_16x16x32_bf16(Hl[kt], bh, a, 0, 0, 0);
        }
      }
      acc[i] = a;
    }
    // stash gates to LDS   (D layout: col = lane&15, row = (lane>>4)*4 + reg)
    #pragma unroll
    for (int i=0;i<4;i++){
      int col = (wv*4+i)*16 + row;
      #pragma unroll
      for (int rr=0;rr<4;rr++)
        sG[(kg*4+rr)*260 + col] = acc[i][rr];
    }
    __syncthreads();
    // LSTM update
    {
      float4 gi = *(const float4*)&sG[urow*260 + uc0];
      float4 gf = *(const float4*)&sG[urow*260 + 64  + uc0];
      float4 gg = *(const float4*)&sG[urow*260 + 128 + uc0];
      float4 go = *(const float4*)&sG[urow*260 + 192 + uc0];
      float gis[4] = {gi.x,gi.y,gi.z,gi.w};
      float gfs[4] = {gf.x,gf.y,gf.z,gf.w};
      float ggs[4] = {gg.x,gg.y,gg.z,gg.w};
      float gos[4] = {go.x,go.y,go.z,go.w};
      unsigned short hh[4], hl[4];
      #pragma unroll
      for (int j=0;j<4;j++){
        float si = 1.f/(1.f + __expf(-gis[j]));
        float sf = 1.f/(1.f + __expf(-gfs[j]));
        float so = 1.f/(1.f + __expf(-gos[j]));
        float tg = tanhf(ggs[j]);
        float cn = sf*creg[j] + si*tg;
        creg[j] = cn;
        hn[j] = so*tanhf(cn);
        hh[j] = f2bf(hn[j]);
        hl[j] = f2bf(hn[j] - bf2f(hh[j]));
      }
      unsigned w0 = (unsigned)hh[0] | ((unsigned)hh[1] << 16);
      unsigned w1 = (unsigned)hh[2] | ((unsigned)hh[3] << 16);
      unsigned v0 = (unsigned)hl[0] | ((unsigned)hl[1] << 16);
      unsigned v1 = (unsigned)hl[2] | ((unsigned)hl[3] << 16);
      *(uint2*)&sHh[urow*72 + uc0] = make_uint2(w0, w1);
      *(uint2*)&sHl[urow*72 + uc0] = make_uint2(v0, v1);
    }
    __syncthreads();
  }
  // final projection: out[r] = sum_j h[r][j]*fc_w[j] + fc_b
  float4 fw = *(const float4*)&fc_w[uc0];
  float v = hn[0]*fw.x + hn[1]*fw.y + hn[2]*fw.z + hn[3]*fw.w;
  v += __shfl_xor(v, 1, 64);
  v += __shfl_xor(v, 2, 64);
  v += __shfl_xor(v, 4, 64);
  v += __shfl_xor(v, 8, 64);
  if ((lane & 15) == 0) out[r0 + urow] = v + fc_b[0];
}

extern "C" void kernel_launch(void* const* d_in, const int* in_sizes, int n_in,
                              void* d_out, int out_size, void* d_ws, size_t ws_size,
                              hipStream_t stream) {
  const float* x    = (const float*)d_in[0];
  const int*   ei   = (const int*)d_in[1];
  const float* W1   = (const float*)d_in[2];
  const float* b1   = (const float*)d_in[3];
  const float* W2   = (const float*)d_in[4];
  const float* b2   = (const float*)d_in[5];
  const float* W_ih = (const float*)d_in[6];
  const float* W_hh = (const float*)d_in[7];
  const float* b_ih = (const float*)d_in[8];
  const float* b_hh = (const float*)d_in[9];
  const float* fc_w = (const float*)d_in[10];
  const float* fc_b = (const float*)d_in[11];
  float* out = (float*)d_out;

  char* ws = (char*)d_ws;
  size_t off = 0;
  auto alloc = [&](size_t bytes)->void* { void* p = ws + off; off += (bytes + 255) & ~255ul; return p; };
  float*          dinv    = (float*)alloc(N_NODES*4);
  int*            cnt     = (int*)alloc(N_NODES*4);
  int*            row_ptr = (int*)alloc((N_NODES+1)*4);
  int*            fillb   = (int*)alloc(N_NODES*4);
  int*            csr_src = (int*)alloc(N_EDGES*4);
  unsigned short* WF      = (unsigned short*)alloc(2*2*16*1024*2);  // 128 KB
  float*          biasT   = (float*)alloc(256*4);
  float*          xd      = (float*)alloc((size_t)BATCH*TSTEPS*N_NODES*4);
  float*          hw2d    = (float*)alloc((size_t)TSTEPS*BATCH*N_NODES*64*4);   // ~30.7 MB
  float*          agg2    = (float*)alloc((size_t)TSTEPS*ROWS*64*4);            // ~30.7 MB

  hipMemsetAsync(cnt,  0, N_NODES*4, stream);
  hipMemsetAsync(fillb,0, N_NODES*4, stream);

  k_count<<<(N_EDGES+255)/256, 256, 0, stream>>>(ei, cnt);
  k_scan <<<1, 1024, 0, stream>>>(cnt, row_ptr, dinv);
  k_fill <<<(N_EDGES+255)/256, 256, 0, stream>>>(ei, row_ptr, fillb, csr_src);
  k_xd   <<<(BATCH*TSTEPS*N_NODES+255)/256, 256, 0, stream>>>(x, dinv, xd);
  k_wfb  <<<17, 256, 0, stream>>>(W_ih, W_hh, b_ih, b_hh, b2, WF, biasT);

  k_hw  <<<TSTEPS*NRB, 256, 0, stream>>>(xd, W1, b1, W2, row_ptr, csr_src, dinv, hw2d);
  k_agg <<<TSTEPS*NRB, 256, 0, stream>>>(hw2d, row_ptr, csr_src, dinv, agg2);
  k_lstm<<<NRB, 256, 0, stream>>>(agg2, WF, biasT, fc_w, fc_b, out);
}